// Round 1
// baseline (1053.586 us; speedup 1.0000x reference)
//
#include <hip/hip_runtime.h>
#include <stdint.h>

#define N_ROWS 12288
#define GSZ (128 * 12288)  // elements per G matrix (bf16)

typedef __attribute__((ext_vector_type(8))) short bf16x8;
typedef __attribute__((ext_vector_type(4))) float f32x4;

__device__ __forceinline__ uint32_t f2bf(float x) {
  union { float f; uint32_t u; } c; c.f = x;
  return (c.u + 0x7FFFu + ((c.u >> 16) & 1u)) >> 16;
}
__device__ __forceinline__ uint32_t pk_bf(float a, float b) {
  return f2bf(a) | (f2bf(b) << 16);
}
__device__ __forceinline__ uint32_t pk_pos(float a, float b) {
  return (a > 0.f ? 0x3F80u : 0u) | (b > 0.f ? 0x3F800000u : 0u);
}
__device__ __forceinline__ uint32_t pk_neg(float a, float b) {
  return (a < 0.f ? 0x3F80u : 0u) | (b < 0.f ? 0x3F800000u : 0u);
}

// ---------------------------------------------------------------------------
// Kernel 1: G_j = feats @ W_j  (fp32 compute), stored bf16 TRANSPOSED:
//   gt[j][n][k] = (feats @ W_j)[k][n],  j=0: node_w top, 1: node_w bottom, 2: edge_w
// grid 768 blocks x 256 thr; block handles 16 k-rows.
// ---------------------------------------------------------------------------
__global__ __launch_bounds__(256) void gw_kernel(
    const float* __restrict__ feats, const float* __restrict__ node_w,
    const float* __restrict__ edge_w, uint16_t* __restrict__ gt) {
  __shared__ float lf[16 * 128];
  const int t = threadIdx.x;
  const int kb = blockIdx.x * 16;
  {
    const float4* src = (const float4*)(feats + (size_t)kb * 128);
    float4* dst = (float4*)lf;
    dst[t] = src[t];
    dst[t + 256] = src[t + 256];
  }
  __syncthreads();
  const int n = t & 127;
  const int rh = t >> 7;  // rows rh*8 .. rh*8+8
  const float* wb[3] = {node_w, node_w + 128 * 128, edge_w};
#pragma unroll
  for (int j = 0; j < 3; ++j) {
    const float* W = wb[j] + n;
    float acc[8];
#pragma unroll
    for (int q = 0; q < 8; ++q) acc[q] = 0.f;
    for (int i = 0; i < 128; i += 4) {
      const float w0 = W[(i + 0) * 128];
      const float w1 = W[(i + 1) * 128];
      const float w2 = W[(i + 2) * 128];
      const float w3 = W[(i + 3) * 128];
#pragma unroll
      for (int q = 0; q < 8; ++q) {
        const float4 f = *(const float4*)&lf[(rh * 8 + q) * 128 + i];
        acc[q] = fmaf(f.w, w3, fmaf(f.z, w2, fmaf(f.y, w1, fmaf(f.x, w0, acc[q]))));
      }
    }
    uint4 o;
    o.x = pk_bf(acc[0], acc[1]);
    o.y = pk_bf(acc[2], acc[3]);
    o.z = pk_bf(acc[4], acc[5]);
    o.w = pk_bf(acc[6], acc[7]);
    *(uint4*)(gt + (size_t)j * GSZ + (size_t)n * N_ROWS + kb + rh * 8) = o;
  }
}

// ---------------------------------------------------------------------------
// Kernel 2: out = relu(pos@G1 + neg@G2 + node_bias) + edge@G3 + edge_bias
// 384 blocks x 128 thr (2 waves). BM=32 rows/block, BK=64, full 128 cols.
// Wave w owns cols [w*64, w*64+64) -> n-frags 4, m-frags 2 (16x16x32 MFMA).
// A tiles (pos/neg/edge bf16) double-buffered in LDS, XOR-swizzled.
// B frags loaded directly from global gt (L2-resident).
// ---------------------------------------------------------------------------
__global__ __launch_bounds__(128, 2) void fgc_main(
    const float* __restrict__ node_adj, const float* __restrict__ edge_adj,
    const uint16_t* __restrict__ gt, const float* __restrict__ node_bias,
    const float* __restrict__ edge_bias, float* __restrict__ out) {
  __shared__ __align__(128) char smem[24576];  // 2 bufs x (pos|neg|edge) x 32x64 bf16
  const int t = threadIdx.x;
  const int l = t & 63;
  const int w = t >> 6;
  const int row0 = blockIdx.x * 32;

  // staging: chunk c covers (row c>>3, k-granule c&7) = 8 consecutive f32
  const int c0 = t, c1 = t + 128;
  const int r0 = c0 >> 3, k80 = c0 & 7;
  const int r1 = c1 >> 3, k81 = c1 & 7;
  const float* npA = node_adj + (size_t)(row0 + r0) * N_ROWS + k80 * 8;
  const float* npB = node_adj + (size_t)(row0 + r1) * N_ROWS + k81 * 8;
  const float* epA = edge_adj + (size_t)(row0 + r0) * N_ROWS + k80 * 8;
  const float* epB = edge_adj + (size_t)(row0 + r1) * N_ROWS + k81 * 8;
  const int wOff0 = r0 * 128 + ((k80 ^ (r0 & 7)) * 16);  // swizzled LDS byte offset
  const int wOff1 = r1 * 128 + ((k81 ^ (r1 & 7)) * 16);

  // A-frag read constants: row = mf*16 + (l&15), k-granule = ks*4 + (l>>4)
  const int arow = (l & 15) * 128;
  const int rx = l & 7;
  const int gq = l >> 4;

  // B lane base: n = w*64 + nf*16 + (l&15), k = kt*64 + ks*32 + gq*8
  const uint16_t* gB = gt + (size_t)(w * 64 + (l & 15)) * N_ROWS + gq * 8;

  f32x4 accn[2][4], acce[2][4];
#pragma unroll
  for (int a = 0; a < 2; ++a)
#pragma unroll
    for (int b = 0; b < 4; ++b) {
      accn[a][b] = {0.f, 0.f, 0.f, 0.f};
      acce[a][b] = {0.f, 0.f, 0.f, 0.f};
    }

  float4 rn0, rn1, rn2, rn3, re0, re1, re2, re3;
  rn0 = *(const float4*)(npA);
  rn1 = *(const float4*)(npA + 4);
  rn2 = *(const float4*)(npB);
  rn3 = *(const float4*)(npB + 4);
  re0 = *(const float4*)(epA);
  re1 = *(const float4*)(epA + 4);
  re2 = *(const float4*)(epB);
  re3 = *(const float4*)(epB + 4);

#pragma unroll 2
  for (int kt = 0; kt < 192; ++kt) {
    char* wb2 = smem + (kt & 1) * 12288;
    {
      uint4 P, Q;
      P.x = pk_pos(rn0.x, rn0.y); P.y = pk_pos(rn0.z, rn0.w);
      P.z = pk_pos(rn1.x, rn1.y); P.w = pk_pos(rn1.z, rn1.w);
      Q.x = pk_neg(rn0.x, rn0.y); Q.y = pk_neg(rn0.z, rn0.w);
      Q.z = pk_neg(rn1.x, rn1.y); Q.w = pk_neg(rn1.z, rn1.w);
      *(uint4*)(wb2 + wOff0) = P;
      *(uint4*)(wb2 + 4096 + wOff0) = Q;
    }
    {
      uint4 P, Q;
      P.x = pk_pos(rn2.x, rn2.y); P.y = pk_pos(rn2.z, rn2.w);
      P.z = pk_pos(rn3.x, rn3.y); P.w = pk_pos(rn3.z, rn3.w);
      Q.x = pk_neg(rn2.x, rn2.y); Q.y = pk_neg(rn2.z, rn2.w);
      Q.z = pk_neg(rn3.x, rn3.y); Q.w = pk_neg(rn3.z, rn3.w);
      *(uint4*)(wb2 + wOff1) = P;
      *(uint4*)(wb2 + 4096 + wOff1) = Q;
    }
    {
      uint4 E;
      E.x = pk_bf(re0.x, re0.y); E.y = pk_bf(re0.z, re0.w);
      E.z = pk_bf(re1.x, re1.y); E.w = pk_bf(re1.z, re1.w);
      *(uint4*)(wb2 + 8192 + wOff0) = E;
      E.x = pk_bf(re2.x, re2.y); E.y = pk_bf(re2.z, re2.w);
      E.z = pk_bf(re3.x, re3.y); E.w = pk_bf(re3.z, re3.w);
      *(uint4*)(wb2 + 8192 + wOff1) = E;
    }
    __syncthreads();
    // prefetch next adjacency tile AFTER the barrier so the barrier's
    // vmcnt(0) drain only sees already-consumed loads.
    if (kt < 191) {
      const size_t ko = (size_t)(kt + 1) * 64;
      rn0 = *(const float4*)(npA + ko);
      rn1 = *(const float4*)(npA + ko + 4);
      rn2 = *(const float4*)(npB + ko);
      rn3 = *(const float4*)(npB + ko + 4);
      re0 = *(const float4*)(epA + ko);
      re1 = *(const float4*)(epA + ko + 4);
      re2 = *(const float4*)(epB + ko);
      re3 = *(const float4*)(epB + ko + 4);
    }
    const char* rb = smem + (kt & 1) * 12288;
#pragma unroll
    for (int ks = 0; ks < 2; ++ks) {
      const int a0 = arow + (((ks * 4 + gq) ^ rx) * 16);
      const bf16x8 ap0 = *(const bf16x8*)(rb + a0);
      const bf16x8 ap1 = *(const bf16x8*)(rb + a0 + 2048);
      const bf16x8 an0 = *(const bf16x8*)(rb + 4096 + a0);
      const bf16x8 an1 = *(const bf16x8*)(rb + 4096 + a0 + 2048);
      const bf16x8 ae0 = *(const bf16x8*)(rb + 8192 + a0);
      const bf16x8 ae1 = *(const bf16x8*)(rb + 8192 + a0 + 2048);
      const uint16_t* gk = gB + kt * 64 + ks * 32;
#pragma unroll
      for (int nf = 0; nf < 4; ++nf) {
        const uint16_t* gp = gk + nf * 16 * N_ROWS;
        const bf16x8 b1 = *(const bf16x8*)(gp);
        const bf16x8 b2 = *(const bf16x8*)(gp + GSZ);
        const bf16x8 b3 = *(const bf16x8*)(gp + 2 * GSZ);
        accn[0][nf] = __builtin_amdgcn_mfma_f32_16x16x32_bf16(ap0, b1, accn[0][nf], 0, 0, 0);
        accn[1][nf] = __builtin_amdgcn_mfma_f32_16x16x32_bf16(ap1, b1, accn[1][nf], 0, 0, 0);
        accn[0][nf] = __builtin_amdgcn_mfma_f32_16x16x32_bf16(an0, b2, accn[0][nf], 0, 0, 0);
        accn[1][nf] = __builtin_amdgcn_mfma_f32_16x16x32_bf16(an1, b2, accn[1][nf], 0, 0, 0);
        acce[0][nf] = __builtin_amdgcn_mfma_f32_16x16x32_bf16(ae0, b3, acce[0][nf], 0, 0, 0);
        acce[1][nf] = __builtin_amdgcn_mfma_f32_16x16x32_bf16(ae1, b3, acce[1][nf], 0, 0, 0);
      }
    }
  }

  // epilogue: C/D frag mapping row=(lane>>4)*4+r, col=lane&15
  const int colb = w * 64 + (l & 15);
#pragma unroll
  for (int nf = 0; nf < 4; ++nf) {
    const int col = colb + nf * 16;
    const float nb = node_bias[col];
    const float eb = edge_bias[col];
#pragma unroll
    for (int mf = 0; mf < 2; ++mf) {
      const f32x4 nv = accn[mf][nf];
      const f32x4 ev = acce[mf][nf];
#pragma unroll
      for (int r = 0; r < 4; ++r) {
        const int row = row0 + mf * 16 + gq * 4 + r;
        out[(size_t)row * 128 + col] = fmaxf(nv[r] + nb, 0.f) + ev[r] + eb;
      }
    }
  }
}

extern "C" void kernel_launch(void* const* d_in, const int* in_sizes, int n_in,
                              void* d_out, int out_size, void* d_ws, size_t ws_size,
                              hipStream_t stream) {
  const float* feats = (const float*)d_in[0];
  const float* node_adj = (const float*)d_in[1];
  const float* edge_adj = (const float*)d_in[2];
  const float* node_w = (const float*)d_in[3];
  const float* node_b = (const float*)d_in[4];
  const float* edge_w = (const float*)d_in[5];
  const float* edge_b = (const float*)d_in[6];
  uint16_t* gt = (uint16_t*)d_ws;  // needs 3*128*12288*2 = 9.44 MB of ws

  gw_kernel<<<768, 256, 0, stream>>>(feats, node_w, edge_w, gt);
  fgc_main<<<384, 128, 0, stream>>>(node_adj, edge_adj, gt, node_b, edge_b,
                                    (float*)d_out);
}

// Round 2
// 581.531 us; speedup vs baseline: 1.8117x; 1.8117x over previous
//
#include <hip/hip_runtime.h>
#include <stdint.h>

#define N_ROWS 12288
#define GSZ (128 * 12288)  // elements per G matrix (bf16)
#define NPART_OFF (9437184 / 4)          // float offset of node partials in ws
#define EPART_OFF ((9437184 + 6291456) / 4)

typedef __attribute__((ext_vector_type(8))) short bf16x8;
typedef __attribute__((ext_vector_type(4))) float f32x4;

__device__ __forceinline__ uint32_t f2bf(float x) {
  union { float f; uint32_t u; } c; c.f = x;
  return (c.u + 0x7FFFu + ((c.u >> 16) & 1u)) >> 16;
}
__device__ __forceinline__ uint32_t pk_bf(float a, float b) {
  return f2bf(a) | (f2bf(b) << 16);
}
__device__ __forceinline__ uint32_t pk_pos(float a, float b) {
  return (a > 0.f ? 0x3F80u : 0u) | (b > 0.f ? 0x3F800000u : 0u);
}
__device__ __forceinline__ uint32_t pk_neg(float a, float b) {
  return (a < 0.f ? 0x3F80u : 0u) | (b < 0.f ? 0x3F800000u : 0u);
}

// ---------------------------------------------------------------------------
// Kernel 1: G_j = feats @ W_j  (fp32 compute), stored bf16 TRANSPOSED:
//   gt[j][n][k] = (feats @ W_j)[k][n],  j=0: node_w top, 1: node_w bottom, 2: edge_w
// ---------------------------------------------------------------------------
__global__ __launch_bounds__(256) void gw_kernel(
    const float* __restrict__ feats, const float* __restrict__ node_w,
    const float* __restrict__ edge_w, uint16_t* __restrict__ gt) {
  __shared__ float lf[16 * 128];
  const int t = threadIdx.x;
  const int kb = blockIdx.x * 16;
  {
    const float4* src = (const float4*)(feats + (size_t)kb * 128);
    float4* dst = (float4*)lf;
    dst[t] = src[t];
    dst[t + 256] = src[t + 256];
  }
  __syncthreads();
  const int n = t & 127;
  const int rh = t >> 7;
  const float* wb[3] = {node_w, node_w + 128 * 128, edge_w};
#pragma unroll
  for (int j = 0; j < 3; ++j) {
    const float* W = wb[j] + n;
    float acc[8];
#pragma unroll
    for (int q = 0; q < 8; ++q) acc[q] = 0.f;
    for (int i = 0; i < 128; i += 4) {
      const float w0 = W[(i + 0) * 128];
      const float w1 = W[(i + 1) * 128];
      const float w2 = W[(i + 2) * 128];
      const float w3 = W[(i + 3) * 128];
#pragma unroll
      for (int q = 0; q < 8; ++q) {
        const float4 f = *(const float4*)&lf[(rh * 8 + q) * 128 + i];
        acc[q] = fmaf(f.w, w3, fmaf(f.z, w2, fmaf(f.y, w1, fmaf(f.x, w0, acc[q]))));
      }
    }
    uint4 o;
    o.x = pk_bf(acc[0], acc[1]);
    o.y = pk_bf(acc[2], acc[3]);
    o.z = pk_bf(acc[4], acc[5]);
    o.w = pk_bf(acc[6], acc[7]);
    *(uint4*)(gt + (size_t)j * GSZ + (size_t)n * N_ROWS + kb + rh * 8) = o;
  }
}

// ---------------------------------------------------------------------------
// Kernel 2: partial = pos@G1+neg@G2 (node) and edge@G3, over a K-slice.
// grid (384 row-tiles, 4 K-slices) x 256 thr (4 waves).
// BM=32 rows/block, BK=64, K-slice = 3072 (48 iters).
// Wave w owns cols [w*32, w*32+32): nf=2, mf=2 (16x16x32 MFMA).
// A tiles (pos|neg|edge bf16) double-buffered in LDS, XOR-swizzled.
// B frags direct from global gt (L2-resident k-slice).
// Accumulates into ws partials via hardware f32 atomics.
// ---------------------------------------------------------------------------
__global__ __launch_bounds__(256) void fgc_main(
    const float* __restrict__ node_adj, const float* __restrict__ edge_adj,
    const uint16_t* __restrict__ gt, float* __restrict__ node_part,
    float* __restrict__ edge_part) {
  __shared__ __align__(128) char smem[24576];  // 2 x (pos|neg|edge) x 32x64 bf16
  const int t = threadIdx.x;
  const int l = t & 63;
  const int w = t >> 6;
  const int row0 = blockIdx.x * 32;
  const size_t k0 = (size_t)blockIdx.y * 3072;  // K-slice origin (floats)

  // staging: thread t owns (row t>>3, granule t&7) = 8 consecutive f32
  const int r = t >> 3, k8 = t & 7;
  const float* np_ = node_adj + (size_t)(row0 + r) * N_ROWS + k0 + k8 * 8;
  const float* ep_ = edge_adj + (size_t)(row0 + r) * N_ROWS + k0 + k8 * 8;
  const int wOff = r * 128 + ((k8 ^ (r & 7)) * 16);  // swizzled LDS byte offset

  // A-frag read: row = mf*16 + (l&15), k-granule = ks*4 + (l>>4)
  const int arow = (l & 15) * 128;
  const int rx = l & 7;
  const int gq = l >> 4;

  // B lane base: n = w*32 + nf*16 + (l&15), k = k0 + kt*64 + ks*32 + gq*8
  const uint16_t* gB = gt + (size_t)(w * 32 + (l & 15)) * N_ROWS + k0 + gq * 8;

  f32x4 accn[2][2], acce[2][2];
#pragma unroll
  for (int a = 0; a < 2; ++a)
#pragma unroll
    for (int b = 0; b < 2; ++b) {
      accn[a][b] = {0.f, 0.f, 0.f, 0.f};
      acce[a][b] = {0.f, 0.f, 0.f, 0.f};
    }

  float4 rn0, rn1, re0, re1;
  rn0 = *(const float4*)(np_);
  rn1 = *(const float4*)(np_ + 4);
  re0 = *(const float4*)(ep_);
  re1 = *(const float4*)(ep_ + 4);

#pragma unroll 2
  for (int kt = 0; kt < 48; ++kt) {
    char* wb2 = smem + (kt & 1) * 12288;
    {
      uint4 P, Q, E;
      P.x = pk_pos(rn0.x, rn0.y); P.y = pk_pos(rn0.z, rn0.w);
      P.z = pk_pos(rn1.x, rn1.y); P.w = pk_pos(rn1.z, rn1.w);
      Q.x = pk_neg(rn0.x, rn0.y); Q.y = pk_neg(rn0.z, rn0.w);
      Q.z = pk_neg(rn1.x, rn1.y); Q.w = pk_neg(rn1.z, rn1.w);
      E.x = pk_bf(re0.x, re0.y);  E.y = pk_bf(re0.z, re0.w);
      E.z = pk_bf(re1.x, re1.y);  E.w = pk_bf(re1.z, re1.w);
      *(uint4*)(wb2 + wOff) = P;
      *(uint4*)(wb2 + 4096 + wOff) = Q;
      *(uint4*)(wb2 + 8192 + wOff) = E;
    }
    __syncthreads();
    // prefetch next tile AFTER the barrier so the barrier's vmcnt drain
    // only covers already-consumed loads.
    if (kt < 47) {
      const size_t ko = (size_t)(kt + 1) * 64;
      rn0 = *(const float4*)(np_ + ko);
      rn1 = *(const float4*)(np_ + ko + 4);
      re0 = *(const float4*)(ep_ + ko);
      re1 = *(const float4*)(ep_ + ko + 4);
    }
    const char* rb = smem + (kt & 1) * 12288;
#pragma unroll
    for (int ks = 0; ks < 2; ++ks) {
      const int a0 = arow + (((ks * 4 + gq) ^ rx) * 16);
      const bf16x8 ap0 = *(const bf16x8*)(rb + a0);
      const bf16x8 ap1 = *(const bf16x8*)(rb + a0 + 2048);
      const bf16x8 an0 = *(const bf16x8*)(rb + 4096 + a0);
      const bf16x8 an1 = *(const bf16x8*)(rb + 4096 + a0 + 2048);
      const bf16x8 ae0 = *(const bf16x8*)(rb + 8192 + a0);
      const bf16x8 ae1 = *(const bf16x8*)(rb + 8192 + a0 + 2048);
      const uint16_t* gk = gB + kt * 64 + ks * 32;
#pragma unroll
      for (int nf = 0; nf < 2; ++nf) {
        const uint16_t* gp = gk + (size_t)nf * 16 * N_ROWS;
        const bf16x8 b1 = *(const bf16x8*)(gp);
        const bf16x8 b2 = *(const bf16x8*)(gp + GSZ);
        const bf16x8 b3 = *(const bf16x8*)(gp + 2 * GSZ);
        accn[0][nf] = __builtin_amdgcn_mfma_f32_16x16x32_bf16(ap0, b1, accn[0][nf], 0, 0, 0);
        accn[1][nf] = __builtin_amdgcn_mfma_f32_16x16x32_bf16(ap1, b1, accn[1][nf], 0, 0, 0);
        accn[0][nf] = __builtin_amdgcn_mfma_f32_16x16x32_bf16(an0, b2, accn[0][nf], 0, 0, 0);
        accn[1][nf] = __builtin_amdgcn_mfma_f32_16x16x32_bf16(an1, b2, accn[1][nf], 0, 0, 0);
        acce[0][nf] = __builtin_amdgcn_mfma_f32_16x16x32_bf16(ae0, b3, acce[0][nf], 0, 0, 0);
        acce[1][nf] = __builtin_amdgcn_mfma_f32_16x16x32_bf16(ae1, b3, acce[1][nf], 0, 0, 0);
      }
    }
  }

  // accumulate partials: C/D frag row=(lane>>4)*4+q, col=lane&15
#pragma unroll
  for (int nf = 0; nf < 2; ++nf) {
    const int col = w * 32 + nf * 16 + (l & 15);
#pragma unroll
    for (int mf = 0; mf < 2; ++mf) {
      const f32x4 nv = accn[mf][nf];
      const f32x4 ev = acce[mf][nf];
#pragma unroll
      for (int q = 0; q < 4; ++q) {
        const size_t idx = (size_t)(row0 + mf * 16 + gq * 4 + q) * 128 + col;
        unsafeAtomicAdd(&node_part[idx], nv[q]);
        unsafeAtomicAdd(&edge_part[idx], ev[q]);
      }
    }
  }
}

// ---------------------------------------------------------------------------
// Kernel 3: out = relu(node_part + node_bias) + edge_part + edge_bias
// ---------------------------------------------------------------------------
__global__ __launch_bounds__(256) void fgc_final(
    const float* __restrict__ node_part, const float* __restrict__ edge_part,
    const float* __restrict__ node_bias, const float* __restrict__ edge_bias,
    float* __restrict__ out) {
  const int idx = blockIdx.x * 256 + threadIdx.x;  // one float4 each
  const int col = (idx * 4) & 127;
  const float4 n = ((const float4*)node_part)[idx];
  const float4 e = ((const float4*)edge_part)[idx];
  const float4 nb = *(const float4*)(node_bias + col);
  const float4 eb = *(const float4*)(edge_bias + col);
  float4 o;
  o.x = fmaxf(n.x + nb.x, 0.f) + e.x + eb.x;
  o.y = fmaxf(n.y + nb.y, 0.f) + e.y + eb.y;
  o.z = fmaxf(n.z + nb.z, 0.f) + e.z + eb.z;
  o.w = fmaxf(n.w + nb.w, 0.f) + e.w + eb.w;
  ((float4*)out)[idx] = o;
}

extern "C" void kernel_launch(void* const* d_in, const int* in_sizes, int n_in,
                              void* d_out, int out_size, void* d_ws, size_t ws_size,
                              hipStream_t stream) {
  const float* feats = (const float*)d_in[0];
  const float* node_adj = (const float*)d_in[1];
  const float* edge_adj = (const float*)d_in[2];
  const float* node_w = (const float*)d_in[3];
  const float* node_b = (const float*)d_in[4];
  const float* edge_w = (const float*)d_in[5];
  const float* edge_b = (const float*)d_in[6];
  uint16_t* gt = (uint16_t*)d_ws;                 // 9.44 MB
  float* node_part = (float*)d_ws + NPART_OFF;    // 6.29 MB
  float* edge_part = (float*)d_ws + EPART_OFF;    // 6.29 MB

  gw_kernel<<<768, 256, 0, stream>>>(feats, node_w, edge_w, gt);
  hipMemsetAsync((char*)d_ws + 9437184, 0, 2 * 6291456, stream);
  fgc_main<<<dim3(384, 4), 256, 0, stream>>>(node_adj, edge_adj, gt,
                                             node_part, edge_part);
  fgc_final<<<1536, 256, 0, stream>>>(node_part, edge_part, node_b, edge_b,
                                      (float*)d_out);
}

// Round 3
// 423.490 us; speedup vs baseline: 2.4879x; 1.3732x over previous
//
#include <hip/hip_runtime.h>
#include <stdint.h>

#define N_ROWS 12288
#define GSZ (128 * 12288)  // elements per G matrix (bf16)
#define NPART_OFF (9437184 / 4)          // float offset of node partials in ws
#define EPART_OFF ((9437184 + 6291456) / 4)

typedef __attribute__((ext_vector_type(8))) short bf16x8;
typedef __attribute__((ext_vector_type(4))) float f32x4;

__device__ __forceinline__ uint32_t f2bf(float x) {
  union { float f; uint32_t u; } c; c.f = x;
  return (c.u + 0x7FFFu + ((c.u >> 16) & 1u)) >> 16;
}
__device__ __forceinline__ uint32_t pk_bf(float a, float b) {
  return f2bf(a) | (f2bf(b) << 16);
}
__device__ __forceinline__ uint32_t pk_pos(float a, float b) {
  return (a > 0.f ? 0x3F80u : 0u) | (b > 0.f ? 0x3F800000u : 0u);
}
__device__ __forceinline__ uint32_t pk_neg(float a, float b) {
  return (a < 0.f ? 0x3F80u : 0u) | (b < 0.f ? 0x3F800000u : 0u);
}

// ---------------------------------------------------------------------------
// Kernel 1: G_j = feats @ W_j  (fp32), stored bf16 TRANSPOSED:
//   gt[j][n][k] = (feats @ W_j)[k][n]
// ---------------------------------------------------------------------------
__global__ __launch_bounds__(256) void gw_kernel(
    const float* __restrict__ feats, const float* __restrict__ node_w,
    const float* __restrict__ edge_w, uint16_t* __restrict__ gt) {
  __shared__ float lf[16 * 128];
  const int t = threadIdx.x;
  const int kb = blockIdx.x * 16;
  {
    const float4* src = (const float4*)(feats + (size_t)kb * 128);
    float4* dst = (float4*)lf;
    dst[t] = src[t];
    dst[t + 256] = src[t + 256];
  }
  __syncthreads();
  const int n = t & 127;
  const int rh = t >> 7;
  const float* wb[3] = {node_w, node_w + 128 * 128, edge_w};
#pragma unroll
  for (int j = 0; j < 3; ++j) {
    const float* W = wb[j] + n;
    float acc[8];
#pragma unroll
    for (int q = 0; q < 8; ++q) acc[q] = 0.f;
    for (int i = 0; i < 128; i += 4) {
      const float w0 = W[(i + 0) * 128];
      const float w1 = W[(i + 1) * 128];
      const float w2 = W[(i + 2) * 128];
      const float w3 = W[(i + 3) * 128];
#pragma unroll
      for (int q = 0; q < 8; ++q) {
        const float4 f = *(const float4*)&lf[(rh * 8 + q) * 128 + i];
        acc[q] = fmaf(f.w, w3, fmaf(f.z, w2, fmaf(f.y, w1, fmaf(f.x, w0, acc[q]))));
      }
    }
    uint4 o;
    o.x = pk_bf(acc[0], acc[1]);
    o.y = pk_bf(acc[2], acc[3]);
    o.z = pk_bf(acc[4], acc[5]);
    o.w = pk_bf(acc[6], acc[7]);
    *(uint4*)(gt + (size_t)j * GSZ + (size_t)n * N_ROWS + kb + rh * 8) = o;
  }
}

// ---------------------------------------------------------------------------
// Kernel 2: K-sliced partials. 768 blocks x 256 thr (4 waves) = exactly
// 3 blocks/CU resident (LDS 48KB, VGPR<=170). BM=64, BK=64, slice=3072.
// XCD-affinity: slice = (bid>>1)&3 so xcd pair {2s,2s+1} only touches
// slice s  ->  per-XCD B working set 2.36MB < 4MB L2.
// Wave w owns cols [w*32,w*32+32): mf=4, nf=2 (16x16x32 MFMA).
// A tiles (pos|neg|edge bf16) double-buffered in LDS, XOR-swizzled.
// ---------------------------------------------------------------------------
__global__ __launch_bounds__(256, 3) void fgc_main(
    const float* __restrict__ node_adj, const float* __restrict__ edge_adj,
    const uint16_t* __restrict__ gt, float* __restrict__ node_part,
    float* __restrict__ edge_part) {
  __shared__ __align__(128) char smem[49152];  // 2 x (pos|neg|edge) x 64x64 bf16
  const int t = threadIdx.x;
  const int l = t & 63;
  const int w = t >> 6;
  const int bid = blockIdx.x;
  const int slice = (bid >> 1) & 3;
  const int rowt = ((bid >> 3) << 1) | (bid & 1);
  const int row0 = rowt * 64;
  const size_t k0 = (size_t)slice * 3072;

  // staging: thread t owns (row t>>2, k-quarter t&3) = 16 consecutive f32
  const int r = t >> 2, q4 = t & 3;
  const float* np_ = node_adj + (size_t)(row0 + r) * N_ROWS + k0 + q4 * 16;
  const float* ep_ = edge_adj + (size_t)(row0 + r) * N_ROWS + k0 + q4 * 16;
  const int g0 = q4 * 2, g1 = q4 * 2 + 1;
  const int wOffA = r * 128 + ((g0 ^ (r & 7)) * 16);  // swizzled LDS byte offs
  const int wOffB = r * 128 + ((g1 ^ (r & 7)) * 16);

  // A-frag read: row = mf*16 + (l&15), col-granule = ks*4 + (l>>4)
  const int arow = (l & 15) * 128;
  const int rx = l & 7;
  const int gq = l >> 4;

  // B lane base: n = w*32 + nf*16 + (l&15), k = k0 + kt*64 + ks*32 + gq*8
  const uint16_t* gB = gt + (size_t)(w * 32 + (l & 15)) * N_ROWS + k0 + gq * 8;

  f32x4 accn[4][2], acce[4][2];
#pragma unroll
  for (int a = 0; a < 4; ++a)
#pragma unroll
    for (int b = 0; b < 2; ++b) {
      accn[a][b] = {0.f, 0.f, 0.f, 0.f};
      acce[a][b] = {0.f, 0.f, 0.f, 0.f};
    }

  float4 rn0, rn1, rn2, rn3, re0, re1, re2, re3;
  rn0 = *(const float4*)(np_);
  rn1 = *(const float4*)(np_ + 4);
  rn2 = *(const float4*)(np_ + 8);
  rn3 = *(const float4*)(np_ + 12);
  re0 = *(const float4*)(ep_);
  re1 = *(const float4*)(ep_ + 4);
  re2 = *(const float4*)(ep_ + 8);
  re3 = *(const float4*)(ep_ + 12);

  for (int kt = 0; kt < 48; ++kt) {
    char* wb2 = smem + (kt & 1) * 24576;
    {
      uint4 P;
      P.x = pk_pos(rn0.x, rn0.y); P.y = pk_pos(rn0.z, rn0.w);
      P.z = pk_pos(rn1.x, rn1.y); P.w = pk_pos(rn1.z, rn1.w);
      *(uint4*)(wb2 + wOffA) = P;
      P.x = pk_pos(rn2.x, rn2.y); P.y = pk_pos(rn2.z, rn2.w);
      P.z = pk_pos(rn3.x, rn3.y); P.w = pk_pos(rn3.z, rn3.w);
      *(uint4*)(wb2 + wOffB) = P;
      P.x = pk_neg(rn0.x, rn0.y); P.y = pk_neg(rn0.z, rn0.w);
      P.z = pk_neg(rn1.x, rn1.y); P.w = pk_neg(rn1.z, rn1.w);
      *(uint4*)(wb2 + 8192 + wOffA) = P;
      P.x = pk_neg(rn2.x, rn2.y); P.y = pk_neg(rn2.z, rn2.w);
      P.z = pk_neg(rn3.x, rn3.y); P.w = pk_neg(rn3.z, rn3.w);
      *(uint4*)(wb2 + 8192 + wOffB) = P;
      P.x = pk_bf(re0.x, re0.y);  P.y = pk_bf(re0.z, re0.w);
      P.z = pk_bf(re1.x, re1.y);  P.w = pk_bf(re1.z, re1.w);
      *(uint4*)(wb2 + 16384 + wOffA) = P;
      P.x = pk_bf(re2.x, re2.y);  P.y = pk_bf(re2.z, re2.w);
      P.z = pk_bf(re3.x, re3.y);  P.w = pk_bf(re3.z, re3.w);
      *(uint4*)(wb2 + 16384 + wOffB) = P;
    }
    __syncthreads();
    // prefetch next tile AFTER the barrier: the barrier's vmcnt drain then
    // only covers already-consumed loads.
    if (kt < 47) {
      const size_t ko = (size_t)(kt + 1) * 64;
      rn0 = *(const float4*)(np_ + ko);
      rn1 = *(const float4*)(np_ + ko + 4);
      rn2 = *(const float4*)(np_ + ko + 8);
      rn3 = *(const float4*)(np_ + ko + 12);
      re0 = *(const float4*)(ep_ + ko);
      re1 = *(const float4*)(ep_ + ko + 4);
      re2 = *(const float4*)(ep_ + ko + 8);
      re3 = *(const float4*)(ep_ + ko + 12);
    }
    const char* rb = smem + (kt & 1) * 24576;
#pragma unroll
    for (int ks = 0; ks < 2; ++ks) {
      const int a0 = arow + (((ks * 4 + gq) ^ rx) * 16);
      const uint16_t* gk = gB + kt * 64 + ks * 32;
      // node: pos @ G1 + neg @ G2
      {
        bf16x8 ap[4], an[4];
#pragma unroll
        for (int mf = 0; mf < 4; ++mf) {
          ap[mf] = *(const bf16x8*)(rb + a0 + mf * 2048);
          an[mf] = *(const bf16x8*)(rb + 8192 + a0 + mf * 2048);
        }
#pragma unroll
        for (int nf = 0; nf < 2; ++nf) {
          const uint16_t* gp = gk + (size_t)nf * 16 * N_ROWS;
          const bf16x8 b1 = *(const bf16x8*)(gp);
          const bf16x8 b2 = *(const bf16x8*)(gp + GSZ);
#pragma unroll
          for (int mf = 0; mf < 4; ++mf)
            accn[mf][nf] = __builtin_amdgcn_mfma_f32_16x16x32_bf16(ap[mf], b1, accn[mf][nf], 0, 0, 0);
#pragma unroll
          for (int mf = 0; mf < 4; ++mf)
            accn[mf][nf] = __builtin_amdgcn_mfma_f32_16x16x32_bf16(an[mf], b2, accn[mf][nf], 0, 0, 0);
        }
      }
      // edge: edge @ G3
      {
        bf16x8 ae[4];
#pragma unroll
        for (int mf = 0; mf < 4; ++mf)
          ae[mf] = *(const bf16x8*)(rb + 16384 + a0 + mf * 2048);
#pragma unroll
        for (int nf = 0; nf < 2; ++nf) {
          const bf16x8 b3 = *(const bf16x8*)(gk + (size_t)nf * 16 * N_ROWS + 2 * GSZ);
#pragma unroll
          for (int mf = 0; mf < 4; ++mf)
            acce[mf][nf] = __builtin_amdgcn_mfma_f32_16x16x32_bf16(ae[mf], b3, acce[mf][nf], 0, 0, 0);
        }
      }
    }
  }

  // accumulate partials: C/D frag row=(lane>>4)*4+q, col=lane&15
#pragma unroll
  for (int nf = 0; nf < 2; ++nf) {
    const int col = w * 32 + nf * 16 + (l & 15);
#pragma unroll
    for (int mf = 0; mf < 4; ++mf) {
      const f32x4 nv = accn[mf][nf];
      const f32x4 ev = acce[mf][nf];
#pragma unroll
      for (int q = 0; q < 4; ++q) {
        const size_t idx = (size_t)(row0 + mf * 16 + gq * 4 + q) * 128 + col;
        unsafeAtomicAdd(&node_part[idx], nv[q]);
        unsafeAtomicAdd(&edge_part[idx], ev[q]);
      }
    }
  }
}

// ---------------------------------------------------------------------------
// Kernel 3: out = relu(node_part + node_bias) + edge_part + edge_bias
// ---------------------------------------------------------------------------
__global__ __launch_bounds__(256) void fgc_final(
    const float* __restrict__ node_part, const float* __restrict__ edge_part,
    const float* __restrict__ node_bias, const float* __restrict__ edge_bias,
    float* __restrict__ out) {
  const int idx = blockIdx.x * 256 + threadIdx.x;  // one float4 each
  const int col = (idx * 4) & 127;
  const float4 n = ((const float4*)node_part)[idx];
  const float4 e = ((const float4*)edge_part)[idx];
  const float4 nb = *(const float4*)(node_bias + col);
  const float4 eb = *(const float4*)(edge_bias + col);
  float4 o;
  o.x = fmaxf(n.x + nb.x, 0.f) + e.x + eb.x;
  o.y = fmaxf(n.y + nb.y, 0.f) + e.y + eb.y;
  o.z = fmaxf(n.z + nb.z, 0.f) + e.z + eb.z;
  o.w = fmaxf(n.w + nb.w, 0.f) + e.w + eb.w;
  ((float4*)out)[idx] = o;
}

extern "C" void kernel_launch(void* const* d_in, const int* in_sizes, int n_in,
                              void* d_out, int out_size, void* d_ws, size_t ws_size,
                              hipStream_t stream) {
  const float* feats = (const float*)d_in[0];
  const float* node_adj = (const float*)d_in[1];
  const float* edge_adj = (const float*)d_in[2];
  const float* node_w = (const float*)d_in[3];
  const float* node_b = (const float*)d_in[4];
  const float* edge_w = (const float*)d_in[5];
  const float* edge_b = (const float*)d_in[6];
  uint16_t* gt = (uint16_t*)d_ws;                 // 9.44 MB
  float* node_part = (float*)d_ws + NPART_OFF;    // 6.29 MB
  float* edge_part = (float*)d_ws + EPART_OFF;    // 6.29 MB

  gw_kernel<<<768, 256, 0, stream>>>(feats, node_w, edge_w, gt);
  hipMemsetAsync((char*)d_ws + 9437184, 0, 2 * 6291456, stream);
  fgc_main<<<768, 256, 0, stream>>>(node_adj, edge_adj, gt,
                                    node_part, edge_part);
  fgc_final<<<1536, 256, 0, stream>>>(node_part, edge_part, node_b, edge_b,
                                      (float*)d_out);
}